// Round 2
// baseline (1353.294 us; speedup 1.0000x reference)
//
#include <hip/hip_runtime.h>
#include <math.h>

// Gated DeltaNet (chunked delta rule, CHUNK=64) for B=2,S=4096,H=16,Dk=Dv=128 fp32.
//
// Decomposition:
//  kernel 1 (gdn_prep), grid = B*H*N = 2048 WGs:
//    per chunk: l2norm(q,k), gc = cumsum(clip(g)), A = -(k_beta k^T ⊙ decay) strict-lower,
//    forward-substitution u = (I-A)^{-1} rhs for rhs ∈ {v*beta, k*beta*e^gc},
//    attn = tril(q k^T ⊙ decay). Writes k_cumdecay, v_ut, attn, gc to d_ws.
//  kernel 2 (gdn_scan), grid = B*H*(Dv/16) = 256 WGs (one per CU):
//    sequential over 64 chunks, state[128][16-slice] in LDS (Dv columns are independent).
//    blockIdx mapping = wb*32 + bh so the 8 sibling WGs of one (b,h) share an XCD L2.
//
// d_ws requirement: 168,296,448 bytes (~160.5 MiB) of float scratch.

#define CC 64

constexpr int B_  = 2;
constexpr int S_  = 4096;
constexpr int H_  = 16;
constexpr int DK_ = 128;
constexpr int DV_ = 128;
constexpr int NC_  = S_ / CC;        // 64 chunks per (b,h)
constexpr int NCH_ = B_ * H_ * NC_;  // 2048 chunks total
constexpr int W_   = 16;             // dv-block width in kernel 2
constexpr int NWB_ = DV_ / W_;       // 8 dv blocks

constexpr float QSCALE = 0.08838834764831845f;  // 1/sqrt(128)

// workspace layout (float offsets)
constexpr size_t WS_KCUM = 0;                                   // [NCH][64][128]
constexpr size_t WS_VUT  = WS_KCUM + (size_t)NCH_ * CC * DK_;   // [NCH][64][128]
constexpr size_t WS_ATT  = WS_VUT  + (size_t)NCH_ * CC * DV_;   // [NCH][64][64]
constexpr size_t WS_GC   = WS_ATT  + (size_t)NCH_ * CC * CC;    // [NCH][64]
constexpr size_t WS_END  = WS_GC   + (size_t)NCH_ * CC;         // total floats

__device__ __forceinline__ float dot4(const float4 a, const float4 b) {
    return a.x * b.x + a.y * b.y + a.z * b.z + a.w * b.w;
}

// ---------------------------------------------------------------------------
// Kernel 1: per-chunk preprocessing (fully chunk-parallel)
// ---------------------------------------------------------------------------
__global__ __launch_bounds__(256) void gdn_prep(
    const float* __restrict__ q, const float* __restrict__ k,
    const float* __restrict__ v, const float* __restrict__ g,
    const float* __restrict__ beta, float* __restrict__ ws)
{
    const int cid = blockIdx.x;          // (b*H + h)*NC + n
    const int n   = cid & (NC_ - 1);
    const int bh  = cid / NC_;
    const int h   = bh & (H_ - 1);
    const int b   = bh / H_;
    const int t   = threadIdx.x;
    const int s0  = n * CC;

    __shared__ float s_k[CC][132];   // normalized k
    __shared__ float s_q[CC][132];   // normalized+scaled q; reused as u2 (k_cumdecay)
    __shared__ float s_u[CC][132];   // u1 (v_ut)
    __shared__ float s_A[CC][65];    // A strict lower
    __shared__ float s_gc[CC];
    __shared__ float s_beta[CC];

    // g (clipped) and beta
    if (t < CC) {
        const size_t gi = ((size_t)b * S_ + s0 + t) * H_ + h;
        float gv = g[gi];
        s_gc[t]   = fminf(fmaxf(gv, -20.f), 20.f);
        s_beta[t] = beta[gi];
    }
    __syncthreads();
    // within-chunk inclusive cumsum, wave-parallel (wave 0 = threads 0..63)
    if (t < CC) {
        float x = s_gc[t];
#pragma unroll
        for (int o = 1; o < CC; o <<= 1) {
            float y = __shfl_up(x, o);
            if (t >= o) x += y;
        }
        s_gc[t] = x;
    }

    // load + l2-normalize q,k : 4 threads per row, 32 elems each
    {
        const int i  = t >> 2;
        const int d0 = (t & 3) * 32;
        const size_t rb = (((size_t)b * S_ + s0 + i) * H_ + h) * (size_t)DK_;
        float4 qr[8], kr[8];
        float ssq = 0.f, ssk = 0.f;
#pragma unroll
        for (int j4 = 0; j4 < 8; ++j4) {
            qr[j4] = *(const float4*)(q + rb + d0 + j4 * 4);
            kr[j4] = *(const float4*)(k + rb + d0 + j4 * 4);
            ssq += dot4(qr[j4], qr[j4]);
            ssk += dot4(kr[j4], kr[j4]);
        }
        ssq += __shfl_xor(ssq, 1); ssq += __shfl_xor(ssq, 2);
        ssk += __shfl_xor(ssk, 1); ssk += __shfl_xor(ssk, 2);
        const float rq = QSCALE / sqrtf(ssq + 1e-6f);
        const float rk = 1.0f   / sqrtf(ssk + 1e-6f);
#pragma unroll
        for (int j4 = 0; j4 < 8; ++j4) {
            *(float4*)&s_q[i][d0 + j4 * 4] =
                make_float4(qr[j4].x * rq, qr[j4].y * rq, qr[j4].z * rq, qr[j4].w * rq);
            *(float4*)&s_k[i][d0 + j4 * 4] =
                make_float4(kr[j4].x * rk, kr[j4].y * rk, kr[j4].z * rk, kr[j4].w * rk);
        }
    }
    __syncthreads();

    // dot matrices: qn·kn^T (attn) and kn·kn^T (A), 16x16 grid of 4x4 register tiles
    {
        const int ti = t >> 4, tj = t & 15;
        const int i0 = ti * 4, j0 = tj * 4;
        float dq[4][4] = {};
        float dkk[4][4] = {};
        if (j0 <= i0 + 3) {  // tile touches lower triangle
#pragma unroll 2
            for (int d4 = 0; d4 < 32; ++d4) {
                float4 qa[4], ka[4], kb[4];
#pragma unroll
                for (int r = 0; r < 4; ++r) {
                    qa[r] = *(const float4*)&s_q[i0 + r][d4 * 4];
                    ka[r] = *(const float4*)&s_k[i0 + r][d4 * 4];
                    kb[r] = *(const float4*)&s_k[j0 + r][d4 * 4];
                }
#pragma unroll
                for (int r = 0; r < 4; ++r)
#pragma unroll
                    for (int c = 0; c < 4; ++c) {
                        dq[r][c]  += dot4(qa[r], kb[c]);
                        dkk[r][c] += dot4(ka[r], kb[c]);
                    }
            }
        }
        const size_t attb = WS_ATT + (size_t)cid * CC * CC;
#pragma unroll
        for (int r = 0; r < 4; ++r)
#pragma unroll
            for (int c = 0; c < 4; ++c) {
                const int i = i0 + r, j = j0 + c;
                float av = 0.f;
                if (j <= i) {
                    const float dec = expf(s_gc[i] - s_gc[j]);
                    av = dq[r][c] * dec;
                    if (j < i) s_A[i][j] = -(s_beta[i] * dkk[r][c]) * dec;
                }
                ws[attb + i * CC + j] = av;
            }
    }
    __syncthreads();

    // forward substitution u = (I-A)^{-1} rhs, right-looking blocked (block=4)
    // threads 0..127: u1 = v*beta (in s_u);  threads 128..255: u2 = k*beta*e^gc (in s_q)
    {
        const int d = t & 127;
        if (t < 128) {
#pragma unroll 4
            for (int i = 0; i < CC; ++i)
                s_u[i][d] = v[(((size_t)b * S_ + s0 + i) * H_ + h) * (size_t)DV_ + d] * s_beta[i];
        } else {
#pragma unroll 4
            for (int i = 0; i < CC; ++i)
                s_q[i][d] = s_k[i][d] * (s_beta[i] * expf(s_gc[i]));
        }
        float* u = (t < 128) ? &s_u[0][0] : &s_q[0][0];
        for (int blk = 0; blk < 16; ++blk) {
            const int i0 = blk * 4;
            const float u0 = u[(i0 + 0) * 132 + d];
            const float u1 = u[(i0 + 1) * 132 + d] + s_A[i0 + 1][i0] * u0;
            const float u2 = u[(i0 + 2) * 132 + d] + s_A[i0 + 2][i0] * u0 + s_A[i0 + 2][i0 + 1] * u1;
            const float u3 = u[(i0 + 3) * 132 + d] + s_A[i0 + 3][i0] * u0 + s_A[i0 + 3][i0 + 1] * u1
                                                   + s_A[i0 + 3][i0 + 2] * u2;
            u[(i0 + 1) * 132 + d] = u1;
            u[(i0 + 2) * 132 + d] = u2;
            u[(i0 + 3) * 132 + d] = u3;
            for (int i = i0 + 4; i < CC; ++i) {
                const float* Ai = s_A[i];
                u[i * 132 + d] += Ai[i0] * u0 + Ai[i0 + 1] * u1 + Ai[i0 + 2] * u2 + Ai[i0 + 3] * u3;
            }
        }
    }
    __syncthreads();

    // write k_cumdecay (s_q), v_ut (s_u), gc
    {
        const size_t kcb = WS_KCUM + (size_t)cid * CC * DK_;
        const size_t vub = WS_VUT  + (size_t)cid * CC * DV_;
        for (int p = t; p < CC * DK_; p += 256) {
            ws[kcb + p] = s_q[p >> 7][p & 127];
            ws[vub + p] = s_u[p >> 7][p & 127];
        }
        if (t < CC) ws[WS_GC + (size_t)cid * CC + t] = s_gc[t];
    }
}

// ---------------------------------------------------------------------------
// Kernel 2: sequential inter-chunk scan; one WG per (b,h,dv-block of 16)
// blockIdx = wb*32 + bh  → all 8 wb-siblings of a bh share blockIdx%8 → same XCD/L2.
// ---------------------------------------------------------------------------
__global__ __launch_bounds__(256) void gdn_scan(
    const float* __restrict__ q, const float* __restrict__ k,
    const float* __restrict__ ws, float* __restrict__ out)
{
    const int bh  = blockIdx.x & 31;
    const int wb  = blockIdx.x >> 5;
    const int h   = bh & (H_ - 1);
    const int b   = bh / H_;
    const int dv0 = wb * W_;
    const int t   = threadIdx.x;

    __shared__ float s_st[W_][132];        // stateT [dv'][dk]
    __shared__ float s_qg[CC][132];        // qn * scale * e^gc
    __shared__ float s_kc[CC][132];        // k_cumdecay
    __shared__ float s_kdT[DK_][CC + 4];   // (kn * e^(gl-gc)) transposed [dk][i]
    __shared__ float s_vnT[W_][CC + 4];    // v_new transposed [dv'][i]
    __shared__ float s_at[CC][CC + 4];     // attn
    __shared__ float s_gc[CC], s_eg[CC], s_edec[CC];
    __shared__ float s_egl;

    for (int p = t; p < W_ * 132; p += 256) (&s_st[0][0])[p] = 0.f;
    __syncthreads();

    const int dp = t & (W_ - 1);   // dv' within block
    const int ig = t >> 4;         // 0..15

    for (int n = 0; n < NC_; ++n) {
        const int cid = bh * NC_ + n;
        const int s0  = n * CC;

        // P0: gc
        if (t < CC) s_gc[t] = ws[WS_GC + (size_t)cid * CC + t];
        __syncthreads();

        // P1: exp tables + stage k_cumdecay, attn (float4 staging)
        if (t < CC) {
            const float gl = s_gc[CC - 1];
            s_eg[t]   = expf(s_gc[t]);
            s_edec[t] = expf(gl - s_gc[t]);
            if (t == 0) s_egl = expf(gl);
        }
        {
            const size_t kcb = WS_KCUM + (size_t)cid * CC * DK_;
#pragma unroll
            for (int it = 0; it < (CC * DK_) / (256 * 4); ++it) {
                const int p4 = (it * 256 + t) * 4;
                *(float4*)&s_kc[p4 >> 7][p4 & 127] = *(const float4*)(ws + kcb + p4);
            }
            const size_t atb = WS_ATT + (size_t)cid * CC * CC;
#pragma unroll
            for (int it = 0; it < (CC * CC) / (256 * 4); ++it) {
                const int p4 = (it * 256 + t) * 4;
                *(float4*)&s_at[p4 >> 6][p4 & 63] = *(const float4*)(ws + atb + p4);
            }
        }
        __syncthreads();

        // P2: recompute qg = qn*scale*e^gc and kdT = (kn*e^(gl-gc))^T from raw q,k
        {
            const int i  = t >> 2;
            const int d0 = (t & 3) * 32;
            const size_t rb = (((size_t)b * S_ + s0 + i) * H_ + h) * (size_t)DK_;
            float4 qr[8], kr[8];
            float ssq = 0.f, ssk = 0.f;
#pragma unroll
            for (int j4 = 0; j4 < 8; ++j4) {
                qr[j4] = *(const float4*)(q + rb + d0 + j4 * 4);
                kr[j4] = *(const float4*)(k + rb + d0 + j4 * 4);
                ssq += dot4(qr[j4], qr[j4]);
                ssk += dot4(kr[j4], kr[j4]);
            }
            ssq += __shfl_xor(ssq, 1); ssq += __shfl_xor(ssq, 2);
            ssk += __shfl_xor(ssk, 1); ssk += __shfl_xor(ssk, 2);
            const float rq  = QSCALE / sqrtf(ssq + 1e-6f) * s_eg[i];
            const float rkd = s_edec[i] / sqrtf(ssk + 1e-6f);
#pragma unroll
            for (int j4 = 0; j4 < 8; ++j4) {
                *(float4*)&s_qg[i][d0 + j4 * 4] =
                    make_float4(qr[j4].x * rq, qr[j4].y * rq, qr[j4].z * rq, qr[j4].w * rq);
                const int d = d0 + j4 * 4;
                s_kdT[d + 0][i] = kr[j4].x * rkd;
                s_kdT[d + 1][i] = kr[j4].y * rkd;
                s_kdT[d + 2][i] = kr[j4].z * rkd;
                s_kdT[d + 3][i] = kr[j4].w * rkd;
            }
        }
        __syncthreads();

        // P3: v_new[i][dp] = v_ut[i][dp] - sum_dk kc[i][dk]*state[dk][dp]
        {
            const size_t vub = WS_VUT + (size_t)cid * CC * DV_ + dv0 + dp;
            float acc[4];
#pragma unroll
            for (int r = 0; r < 4; ++r) acc[r] = ws[vub + (size_t)(ig * 4 + r) * DV_];
            for (int d4 = 0; d4 < 32; ++d4) {
                const float4 st = *(const float4*)&s_st[dp][d4 * 4];
#pragma unroll
                for (int r = 0; r < 4; ++r) {
                    const float4 kc = *(const float4*)&s_kc[ig * 4 + r][d4 * 4];
                    acc[r] -= dot4(kc, st);
                }
            }
#pragma unroll
            for (int r = 0; r < 4; ++r) s_vnT[dp][ig * 4 + r] = acc[r];
        }
        __syncthreads();

        // P4: out[i][dp] = qg[i]·state[:,dp] + attn[i]·v_new[:,dp]
        {
            float acc[4] = {0.f, 0.f, 0.f, 0.f};
            for (int d4 = 0; d4 < 32; ++d4) {
                const float4 st = *(const float4*)&s_st[dp][d4 * 4];
#pragma unroll
                for (int r = 0; r < 4; ++r) {
                    const float4 qg = *(const float4*)&s_qg[ig * 4 + r][d4 * 4];
                    acc[r] += dot4(qg, st);
                }
            }
            for (int j4 = 0; j4 < 16; ++j4) {
                const float4 vn = *(const float4*)&s_vnT[dp][j4 * 4];
#pragma unroll
                for (int r = 0; r < 4; ++r) {
                    const float4 at = *(const float4*)&s_at[ig * 4 + r][j4 * 4];
                    acc[r] += dot4(at, vn);
                }
            }
#pragma unroll
            for (int r = 0; r < 4; ++r) {
                const int i = ig * 4 + r;
                out[(((size_t)b * S_ + s0 + i) * H_ + h) * (size_t)DV_ + dv0 + dp] = acc[r];
            }
        }
        __syncthreads();

        // P5: state[dk][dp] = state[dk][dp]*e^gl + sum_i kdT[dk][i]*v_new[i][dp]
        {
            const float egl = s_egl;
            float acc[8];
#pragma unroll
            for (int a = 0; a < 8; ++a) acc[a] = s_st[dp][ig + 16 * a] * egl;
            for (int j4 = 0; j4 < 16; ++j4) {
                const float4 vn = *(const float4*)&s_vnT[dp][j4 * 4];
#pragma unroll
                for (int a = 0; a < 8; ++a) {
                    const float4 kd = *(const float4*)&s_kdT[ig + 16 * a][j4 * 4];
                    acc[a] += dot4(kd, vn);
                }
            }
#pragma unroll
            for (int a = 0; a < 8; ++a) s_st[dp][ig + 16 * a] = acc[a];
        }
        __syncthreads();
    }
}

// ---------------------------------------------------------------------------
extern "C" void kernel_launch(void* const* d_in, const int* in_sizes, int n_in,
                              void* d_out, int out_size, void* d_ws, size_t ws_size,
                              hipStream_t stream) {
    const float* q    = (const float*)d_in[0];
    const float* k    = (const float*)d_in[1];
    const float* v    = (const float*)d_in[2];
    const float* g    = (const float*)d_in[3];
    const float* beta = (const float*)d_in[4];
    float* ws  = (float*)d_ws;
    float* out = (float*)d_out;

    // requires ws_size >= WS_END*4 = 168,296,448 bytes (~160.5 MiB)
    gdn_prep<<<NCH_, 256, 0, stream>>>(q, k, v, g, beta, ws);
    gdn_scan<<<B_ * H_ * NWB_, 256, 0, stream>>>(q, k, ws, out);
}

// Round 4
// 1086.022 us; speedup vs baseline: 1.2461x; 1.2461x over previous
//
#include <hip/hip_runtime.h>
#include <math.h>

// Gated DeltaNet (chunked delta rule, CHUNK=64) for B=2,S=4096,H=16,Dk=Dv=128 fp32.
// Round 4 = round 3 resubmitted (GPU was unavailable; no measurement yet):
// 512-thread WGs (8 waves), k-split register-tiled GEMMs with quad shuffle
// reduction, fused [kc;qg]*state GEMM, 3 barriers/chunk, state [dk][dp].

#define CC 64

constexpr int B_  = 2;
constexpr int S_  = 4096;
constexpr int H_  = 16;
constexpr int DK_ = 128;
constexpr int DV_ = 128;
constexpr int NC_  = S_ / CC;        // 64 chunks per (b,h)
constexpr int NCH_ = B_ * H_ * NC_;  // 2048 chunks total
constexpr int W_   = 16;             // dv-block width in kernel 2
constexpr int NWB_ = DV_ / W_;       // 8 dv blocks

constexpr float QSCALE = 0.08838834764831845f;  // 1/sqrt(128)

// workspace layout (float offsets) — total 168,296,448 bytes
constexpr size_t WS_KCUM = 0;                                   // [NCH][64][128]
constexpr size_t WS_VUT  = WS_KCUM + (size_t)NCH_ * CC * DK_;   // [NCH][64][128]
constexpr size_t WS_ATT  = WS_VUT  + (size_t)NCH_ * CC * DV_;   // [NCH][64][64]
constexpr size_t WS_GC   = WS_ATT  + (size_t)NCH_ * CC * CC;    // [NCH][64]

__device__ __forceinline__ void ld4(float* d, const float* s) {
    float4 t = *(const float4*)s;
    d[0] = t.x; d[1] = t.y; d[2] = t.z; d[3] = t.w;
}
__device__ __forceinline__ void st4(float* d, const float* s) {
    *(float4*)d = make_float4(s[0], s[1], s[2], s[3]);
}

// ---------------------------------------------------------------------------
// Kernel 1: per-chunk preprocessing (fully chunk-parallel), 512 threads
// ---------------------------------------------------------------------------
__global__ __launch_bounds__(512) void gdn_prep(
    const float* __restrict__ q, const float* __restrict__ k,
    const float* __restrict__ v, const float* __restrict__ g,
    const float* __restrict__ beta, float* __restrict__ ws)
{
    const int cid = blockIdx.x;          // (b*H + h)*NC + n
    const int n   = cid & (NC_ - 1);
    const int bh  = cid / NC_;
    const int h   = bh & (H_ - 1);
    const int b   = bh / H_;
    const int t   = threadIdx.x;
    const int s0  = n * CC;

    __shared__ float s_k[CC][132];   // kn; later in-place u2 (k_cumdecay)
    __shared__ float s_q[CC][132];   // qn*QSCALE; later u1 (v_ut)
    __shared__ float s_A[CC][66];    // A strict lower
    __shared__ float s_at[CC][68];   // attn staging (coalesced global store)
    __shared__ float s_gc[CC];
    __shared__ float s_beta[CC];

    // g (clipped) and beta, then wave-parallel inclusive cumsum
    if (t < CC) {
        const size_t gi = ((size_t)b * S_ + s0 + t) * H_ + h;
        float gv = g[gi];
        float x = fminf(fmaxf(gv, -20.f), 20.f);
        s_beta[t] = beta[gi];
#pragma unroll
        for (int o = 1; o < CC; o <<= 1) {
            float y = __shfl_up(x, o);
            if (t >= o) x += y;
        }
        s_gc[t] = x;
    }

    // load + l2-normalize q,k : 8 threads per row, 16 elems each
    {
        const int i  = t >> 3;
        const int d0 = (t & 7) * 16;
        const size_t rb = (((size_t)b * S_ + s0 + i) * H_ + h) * (size_t)DK_;
        float qr[4][4], kr[4][4];
        float ssq = 0.f, ssk = 0.f;
#pragma unroll
        for (int j4 = 0; j4 < 4; ++j4) {
            ld4(qr[j4], q + rb + d0 + j4 * 4);
            ld4(kr[j4], k + rb + d0 + j4 * 4);
#pragma unroll
            for (int c = 0; c < 4; ++c) { ssq += qr[j4][c] * qr[j4][c]; ssk += kr[j4][c] * kr[j4][c]; }
        }
        ssq += __shfl_xor(ssq, 1); ssq += __shfl_xor(ssq, 2); ssq += __shfl_xor(ssq, 4);
        ssk += __shfl_xor(ssk, 1); ssk += __shfl_xor(ssk, 2); ssk += __shfl_xor(ssk, 4);
        const float rq = QSCALE / sqrtf(ssq + 1e-6f);
        const float rk = 1.0f   / sqrtf(ssk + 1e-6f);
#pragma unroll
        for (int j4 = 0; j4 < 4; ++j4) {
            float tq[4], tk[4];
#pragma unroll
            for (int c = 0; c < 4; ++c) { tq[c] = qr[j4][c] * rq; tk[c] = kr[j4][c] * rk; }
            st4(&s_q[i][d0 + j4 * 4], tq);
            st4(&s_k[i][d0 + j4 * 4], tk);
        }
    }
    __syncthreads();

    // dots: dq = qn*s . kn^T, dkk = kn . kn^T. 16x16 grid of 4x4 tiles,
    // k-split 2, wave = 4 ti x 8 tj x 2 ks (balanced row-spread, low conflicts)
    {
        const int ks   = t & 1;
        const int slot = t >> 1;
        const int tj = (slot & 7) | (((slot >> 5) & 1) << 3);
        const int ti = ((slot >> 3) & 3) | ((slot >> 6) << 2);
        const int i0 = ti * 4, j0 = tj * 4;
        float dq[4][4] = {}, dkk[4][4] = {};
        if (j0 <= i0 + 3) {
            for (int s = 0; s < 16; ++s) {
                const int dd = (ks + 2 * s) * 4;
                float qa[4][4], ka[4][4], kb[4][4];
#pragma unroll
                for (int r = 0; r < 4; ++r) { ld4(qa[r], &s_q[i0 + r][dd]); ld4(ka[r], &s_k[i0 + r][dd]); }
#pragma unroll
                for (int c = 0; c < 4; ++c) ld4(kb[c], &s_k[j0 + c][dd]);
#pragma unroll
                for (int r = 0; r < 4; ++r)
#pragma unroll
                    for (int c = 0; c < 4; ++c) {
                        dq[r][c]  += qa[r][0]*kb[c][0] + qa[r][1]*kb[c][1] + qa[r][2]*kb[c][2] + qa[r][3]*kb[c][3];
                        dkk[r][c] += ka[r][0]*kb[c][0] + ka[r][1]*kb[c][1] + ka[r][2]*kb[c][2] + ka[r][3]*kb[c][3];
                    }
            }
        }
#pragma unroll
        for (int r = 0; r < 4; ++r)
#pragma unroll
            for (int c = 0; c < 4; ++c) {
                float x = dq[r][c];  x += __shfl_xor(x, 1); dq[r][c] = x;
                float y = dkk[r][c]; y += __shfl_xor(y, 1); dkk[r][c] = y;
            }
        // each ks lane writes 2 of the 4 cols
#pragma unroll
        for (int r = 0; r < 4; ++r)
#pragma unroll
            for (int cc = 0; cc < 2; ++cc) {
                const int c = ks * 2 + cc;
                const int i = i0 + r, j = j0 + c;
                float av = 0.f;
                if (j <= i) {
                    const float dec = expf(s_gc[i] - s_gc[j]);
                    av = dq[r][c] * dec;
                    if (j < i) s_A[i][j] = -(s_beta[i] * dkk[r][c]) * dec;
                }
                s_at[i][j] = av;
            }
    }
    __syncthreads();

    // u inits: u1 = v*beta into s_q (overwrites qn), u2 = kn*beta*e^gc in s_k
    {
        const size_t vb = (((size_t)b * S_ + s0) * H_ + h) * (size_t)DV_;
#pragma unroll
        for (int r = 0; r < 4; ++r) {
            const int f4i = r * 512 + t;           // 2048 float4s
            const int row = f4i >> 5, c4 = (f4i & 31) * 4;
            float tv[4];
            ld4(tv, v + vb + (size_t)row * H_ * DV_ + c4);
            const float be = s_beta[row];
            tv[0] *= be; tv[1] *= be; tv[2] *= be; tv[3] *= be;
            st4(&s_q[row][c4], tv);
            float tk[4];
            ld4(tk, &s_k[row][c4]);
            const float sc = be * expf(s_gc[row]);
            tk[0] *= sc; tk[1] *= sc; tk[2] *= sc; tk[3] *= sc;
            st4(&s_k[row][c4], tk);
        }
    }
    __syncthreads();

    // forward substitution u = (I-A)^{-1} u, blocked (block=4), t<256
    if (t < 256) {
        const int d = t & 127;
        float* u = (t < 128) ? &s_q[0][0] : &s_k[0][0];
        for (int blk = 0; blk < 16; ++blk) {
            const int i0 = blk * 4;
            const float u0 = u[(i0 + 0) * 132 + d];
            const float u1 = u[(i0 + 1) * 132 + d] + s_A[i0 + 1][i0] * u0;
            const float u2 = u[(i0 + 2) * 132 + d] + s_A[i0 + 2][i0] * u0 + s_A[i0 + 2][i0 + 1] * u1;
            const float u3 = u[(i0 + 3) * 132 + d] + s_A[i0 + 3][i0] * u0 + s_A[i0 + 3][i0 + 1] * u1
                                                   + s_A[i0 + 3][i0 + 2] * u2;
            u[(i0 + 1) * 132 + d] = u1;
            u[(i0 + 2) * 132 + d] = u2;
            u[(i0 + 3) * 132 + d] = u3;
            for (int i = i0 + 4; i < CC; ++i) {
                const float* Ai = s_A[i];
                u[i * 132 + d] += Ai[i0] * u0 + Ai[i0 + 1] * u1 + Ai[i0 + 2] * u2 + Ai[i0 + 3] * u3;
            }
        }
    }
    __syncthreads();

    // coalesced stores: kc (s_k), vut (s_q), attn (s_at), gc
    {
        const size_t kcb = WS_KCUM + (size_t)cid * CC * DK_;
        const size_t vub = WS_VUT  + (size_t)cid * CC * DV_;
#pragma unroll
        for (int r = 0; r < 4; ++r) {
            const int f4i = r * 512 + t;
            const int row = f4i >> 5, c4 = (f4i & 31) * 4;
            float tk[4], tv[4];
            ld4(tk, &s_k[row][c4]);
            ld4(tv, &s_q[row][c4]);
            st4((float*)(ws + kcb) + f4i * 4, tk);
            st4((float*)(ws + vub) + f4i * 4, tv);
        }
        const size_t atb = WS_ATT + (size_t)cid * CC * CC;
#pragma unroll
        for (int r = 0; r < 2; ++r) {
            const int f4i = r * 512 + t;           // 1024 float4s
            const int row = f4i >> 4, c4 = (f4i & 15) * 4;
            float ta[4];
            ld4(ta, &s_at[row][c4]);
            st4((float*)(ws + atb) + f4i * 4, ta);
        }
        if (t < CC) ws[WS_GC + (size_t)cid * CC + t] = s_gc[t];
    }
}

// ---------------------------------------------------------------------------
// Kernel 2: sequential inter-chunk scan; one WG per (b,h,dv-block of 16),
// 512 threads (8 waves). blockIdx = wb*32 + bh (XCD-shared L2 across siblings).
// ---------------------------------------------------------------------------
__global__ __launch_bounds__(512) void gdn_scan(
    const float* __restrict__ q, const float* __restrict__ k,
    const float* __restrict__ ws, float* __restrict__ out)
{
    const int bh  = blockIdx.x & 31;
    const int wb  = blockIdx.x >> 5;
    const int h   = bh & (H_ - 1);
    const int b   = bh / H_;
    const int dv0 = wb * W_;
    const int t   = threadIdx.x;

    const int ks   = t & 3;            // k-split lane (quad)
    const int slot = t >> 2;           // 128 slots
    const int jg   = slot & 3;         // dp group
    const int mg   = slot >> 2;        // 0..31
    const int dp0  = jg * 4;

    __shared__ float s_kq[128][132];   // rows 0-63: kc, rows 64-127: qg
    __shared__ float s_kd[64][132];    // kn * e^(gl-gc), row-major
    __shared__ float s_at[64][68];     // attn
    __shared__ float s_st[128][20];    // state [dk][dp]
    __shared__ float s_vn[64][20];     // v_new [i][dp]
    __shared__ float s_o[64][20];      // inter (qg . state) [i][dp]

    for (int p = t; p < 128 * 20; p += 512) (&s_st[0][0])[p] = 0.f;
    __syncthreads();

    for (int n = 0; n < NC_; ++n) {
        const int cid = bh * NC_ + n;
        const int s0  = n * CC;

        // ---------------- Phase AB: staging + qg/kd compute ----------------
        const float gl  = ws[WS_GC + (size_t)cid * CC + (CC - 1)];
        const float egl = expf(gl);

        // stage kc -> s_kq[0:64]
        {
            const float* kcb = ws + WS_KCUM + (size_t)cid * CC * DK_;
#pragma unroll
            for (int r = 0; r < 4; ++r) {
                const int f4i = r * 512 + t;       // 2048 float4s
                const int row = f4i >> 5, c4 = (f4i & 31) * 4;
                float tv[4];
                ld4(tv, kcb + f4i * 4);
                st4(&s_kq[row][c4], tv);
            }
            const float* atb = ws + WS_ATT + (size_t)cid * CC * CC;
#pragma unroll
            for (int r = 0; r < 2; ++r) {
                const int f4i = r * 512 + t;       // 1024 float4s
                const int row = f4i >> 4, c4 = (f4i & 15) * 4;
                float tv[4];
                ld4(tv, atb + f4i * 4);
                st4(&s_at[row][c4], tv);
            }
        }

        // prefetch vut slice for this thread's C-phase output tile
        float vut_[4][4];
        if (ks == 0 && mg < 16) {
            const float* vub = ws + WS_VUT + (size_t)cid * CC * DV_;
            const int i0 = mg * 4;
#pragma unroll
            for (int r = 0; r < 4; ++r) ld4(vut_[r], vub + (size_t)(i0 + r) * DV_ + dv0 + dp0);
        }

        // qg = qn*QSCALE*e^gc -> s_kq[64+i]; kd = kn*e^(gl-gc) -> s_kd[i]
        {
            const int i  = t >> 3;
            const int d0 = (t & 7) * 16;
            const float gci = ws[WS_GC + (size_t)cid * CC + i];
            const size_t rb = (((size_t)b * S_ + s0 + i) * H_ + h) * (size_t)DK_;
            float qr[4][4], kr[4][4];
            float ssq = 0.f, ssk = 0.f;
#pragma unroll
            for (int j4 = 0; j4 < 4; ++j4) {
                ld4(qr[j4], q + rb + d0 + j4 * 4);
                ld4(kr[j4], k + rb + d0 + j4 * 4);
#pragma unroll
                for (int c = 0; c < 4; ++c) { ssq += qr[j4][c] * qr[j4][c]; ssk += kr[j4][c] * kr[j4][c]; }
            }
            ssq += __shfl_xor(ssq, 1); ssq += __shfl_xor(ssq, 2); ssq += __shfl_xor(ssq, 4);
            ssk += __shfl_xor(ssk, 1); ssk += __shfl_xor(ssk, 2); ssk += __shfl_xor(ssk, 4);
            const float rq  = QSCALE / sqrtf(ssq + 1e-6f) * expf(gci);
            const float rkd = expf(gl - gci) / sqrtf(ssk + 1e-6f);
#pragma unroll
            for (int j4 = 0; j4 < 4; ++j4) {
                float tq[4], tk[4];
#pragma unroll
                for (int c = 0; c < 4; ++c) { tq[c] = qr[j4][c] * rq; tk[c] = kr[j4][c] * rkd; }
                st4(&s_kq[64 + i][d0 + j4 * 4], tq);
                st4(&s_kd[i][d0 + j4 * 4], tk);
            }
        }
        __syncthreads();   // B1

        // ---------------- Phase C: X = [kc;qg](128x128) . st(128x16) --------
        // tile 4m x 4dp, k-split 4 (quad shuffle reduce)
        {
            const int m0 = mg * 4;
            float acc[4][4] = {};
            for (int s = 0; s < 8; ++s) {
                const int dk = (ks + 4 * s) * 4;
                float Bv[4][4], Av[4][4];
#pragma unroll
                for (int kk = 0; kk < 4; ++kk) ld4(Bv[kk], &s_st[dk + kk][dp0]);
#pragma unroll
                for (int r = 0; r < 4; ++r) ld4(Av[r], &s_kq[m0 + r][dk]);
#pragma unroll
                for (int r = 0; r < 4; ++r)
#pragma unroll
                    for (int c = 0; c < 4; ++c)
                        acc[r][c] += Av[r][0]*Bv[0][c] + Av[r][1]*Bv[1][c]
                                   + Av[r][2]*Bv[2][c] + Av[r][3]*Bv[3][c];
            }
#pragma unroll
            for (int r = 0; r < 4; ++r)
#pragma unroll
                for (int c = 0; c < 4; ++c) {
                    float x = acc[r][c];
                    x += __shfl_xor(x, 1); x += __shfl_xor(x, 2);
                    acc[r][c] = x;
                }
            if (ks == 0) {
                if (mg < 16) {           // v_new rows
                    const int i0 = mg * 4;
#pragma unroll
                    for (int r = 0; r < 4; ++r) {
                        float tv[4];
#pragma unroll
                        for (int c = 0; c < 4; ++c) tv[c] = vut_[r][c] - acc[r][c];
                        st4(&s_vn[i0 + r][dp0], tv);
                    }
                } else {                 // inter rows
                    const int i0 = (mg - 16) * 4;
#pragma unroll
                    for (int r = 0; r < 4; ++r) st4(&s_o[i0 + r][dp0], acc[r]);
                }
            }
        }
        __syncthreads();   // B2

        // ---------------- Phase D: out + state update ----------------------
        // P4b: out[i][dp] = s_o + attn . v_new ; tile 2i x 4dp, k-split 4
        {
            const int i0b = mg * 2;
            float bacc[2][4] = {};
            for (int s = 0; s < 4; ++s) {
                const int j = (ks + 4 * s) * 4;
                float vnv[4][4], atv[2][4];
#pragma unroll
                for (int kk = 0; kk < 4; ++kk) ld4(vnv[kk], &s_vn[j + kk][dp0]);
#pragma unroll
                for (int r = 0; r < 2; ++r) ld4(atv[r], &s_at[i0b + r][j]);
#pragma unroll
                for (int r = 0; r < 2; ++r)
#pragma unroll
                    for (int c = 0; c < 4; ++c)
                        bacc[r][c] += atv[r][0]*vnv[0][c] + atv[r][1]*vnv[1][c]
                                    + atv[r][2]*vnv[2][c] + atv[r][3]*vnv[3][c];
            }
#pragma unroll
            for (int r = 0; r < 2; ++r)
#pragma unroll
                for (int c = 0; c < 4; ++c) {
                    float x = bacc[r][c];
                    x += __shfl_xor(x, 1); x += __shfl_xor(x, 2);
                    bacc[r][c] = x;
                }
            if (ks == 0) {
#pragma unroll
                for (int r = 0; r < 2; ++r) {
                    float ov[4];
                    ld4(ov, &s_o[i0b + r][dp0]);
#pragma unroll
                    for (int c = 0; c < 4; ++c) ov[c] += bacc[r][c];
                    st4(out + (((size_t)b * S_ + s0 + i0b + r) * H_ + h) * (size_t)DV_ + dv0 + dp0, ov);
                }
            }
        }
        // P5: st[dk][dp] = st*egl + sum_i kd[i][dk] * vn[i][dp]; tile 4dk x 4dp, ks4
        {
            const int dk0 = mg * 4;
            float cacc[4][4] = {};
            for (int s = 0; s < 4; ++s) {
                const int ib = (ks + 4 * s) * 4;
#pragma unroll
                for (int kk = 0; kk < 4; ++kk) {
                    float kdv[4], vnv[4];
                    ld4(kdv, &s_kd[ib + kk][dk0]);
                    ld4(vnv, &s_vn[ib + kk][dp0]);
#pragma unroll
                    for (int r = 0; r < 4; ++r)
#pragma unroll
                        for (int c = 0; c < 4; ++c)
                            cacc[r][c] += kdv[r] * vnv[c];
                }
            }
#pragma unroll
            for (int r = 0; r < 4; ++r)
#pragma unroll
                for (int c = 0; c < 4; ++c) {
                    float x = cacc[r][c];
                    x += __shfl_xor(x, 1); x += __shfl_xor(x, 2);
                    cacc[r][c] = x;
                }
            if (ks == 0) {
#pragma unroll
                for (int r = 0; r < 4; ++r) {
                    float st_[4];
                    ld4(st_, &s_st[dk0 + r][dp0]);
#pragma unroll
                    for (int c = 0; c < 4; ++c) st_[c] = st_[c] * egl + cacc[r][c];
                    st4(&s_st[dk0 + r][dp0], st_);
                }
            }
        }
        __syncthreads();   // B3
    }
}

// ---------------------------------------------------------------------------
extern "C" void kernel_launch(void* const* d_in, const int* in_sizes, int n_in,
                              void* d_out, int out_size, void* d_ws, size_t ws_size,
                              hipStream_t stream) {
    const float* q    = (const float*)d_in[0];
    const float* k    = (const float*)d_in[1];
    const float* v    = (const float*)d_in[2];
    const float* g    = (const float*)d_in[3];
    const float* beta = (const float*)d_in[4];
    float* ws  = (float*)d_ws;
    float* out = (float*)d_out;

    gdn_prep<<<NCH_, 512, 0, stream>>>(q, k, v, g, beta, ws);
    gdn_scan<<<B_ * H_ * NWB_, 512, 0, stream>>>(q, k, ws, out);
}